// Round 3
// baseline (1418.085 us; speedup 1.0000x reference)
//
#include <hip/hip_runtime.h>
#include <math.h>

#define BATCH 256
#define SEQ 512
#define SD_STRIDE 56   // dt[6] cos[6] sin[6] Cc[18] term[18] pad[2]
#define PI_F 3.14159265358979323846f

// ---- cross-lane helpers -----------------------------------------------------
template<int CTRL>
__device__ __forceinline__ float fdpp(float v) {
    return __int_as_float(__builtin_amdgcn_mov_dpp(__float_as_int(v), CTRL, 0xF, 0xF, true));
}
// xor-shuffle on lane masks <32: 1,2,3 quad_perm DPP; 8 row_ror:8 DPP; else ds_swizzle
template<int M>
__device__ __forceinline__ float shxm(float v) {
    if constexpr (M == 1)      return fdpp<0xB1>(v);
    else if constexpr (M == 2) return fdpp<0x4E>(v);
    else if constexpr (M == 3) return fdpp<0x1B>(v);
    else if constexpr (M == 8) return fdpp<0x128>(v);
    else return __int_as_float(__builtin_amdgcn_ds_swizzle(__float_as_int(v), (M << 10) | 0x1F));
}
template<int L>
__device__ __forceinline__ float rdl(float v) {
    return __int_as_float(__builtin_amdgcn_readlane(__float_as_int(v), L));
}
// QSVT per-degree CNOT-block permutation (amp-index source map) — GF(2)-linear
__device__ __forceinline__ int permf(int x) {
    const int cs[11] = {0,1,2,3,4,5,5,4,3,2,1};
    const int ts[11] = {1,2,3,4,5,0,4,3,2,1,0};
#pragma unroll
    for (int k = 10; k >= 0; k--) {
        int cb = (x >> (5 - cs[k])) & 1;
        x ^= cb << (5 - ts[k]);
    }
    return x;
}
// fused 2x(1q gate): out = c00*v + c10*aflip + c01*bflip + c11*abflip (complex)
__device__ __forceinline__ void cmul4(const float* c,
    float vr, float vi, float ar, float ai, float br, float bi, float cr, float ci,
    float& nr, float& ni) {
    nr = c[0]*vr - c[1]*vi + c[2]*ar - c[3]*ai + c[4]*br - c[5]*bi + c[6]*cr - c[7]*ci;
    ni = c[0]*vi + c[1]*vr + c[2]*ai + c[3]*ar + c[4]*bi + c[5]*br + c[6]*ci + c[7]*cr;
}
// fused CRX pair: v=self, b=mid-flip, c=last-flip, d=both-flip
__device__ __forceinline__ void ringapply(const float* rc,
    float vr, float vi, float br, float bi, float cr, float ci, float dr, float di,
    float& nr, float& ni) {
    nr = rc[0]*vr - rc[1]*bi - rc[2]*ci + rc[3]*dr;
    ni = rc[0]*vi + rc[1]*br + rc[2]*cr + rc[3]*di;
}

// ---------------------------------------------------------------------------
__global__ __launch_bounds__(256) void prep_kernel(
    const float* __restrict__ angles, const float* __restrict__ Wx,
    const float* __restrict__ Wdt, const float* __restrict__ bdt,
    const float* __restrict__ D, const float* __restrict__ Wc,
    float* __restrict__ sd)
{
    int gid = blockIdx.x * blockDim.x + threadIdx.x;
    if (gid >= BATCH * SEQ) return;
    const float* a = angles + (size_t)gid * 6;
    float ang[6];
#pragma unroll
    for (int i = 0; i < 6; i++) ang[i] = a[i];
    float dtr[3];
#pragma unroll
    for (int r = 0; r < 3; r++) {
        float s = 0.f;
#pragma unroll
        for (int k = 0; k < 6; k++) s += ang[k] * Wx[r * 6 + k];
        dtr[r] = s;
    }
    float* rec = sd + (size_t)gid * SD_STRIDE;
    float dtv[6];
#pragma unroll
    for (int i = 0; i < 6; i++) {
        float x = bdt[i];
#pragma unroll
        for (int r = 0; r < 3; r++) x += dtr[r] * Wdt[i * 3 + r];
        float sp = (x > 15.f) ? x : log1pf(expf(x));
        dtv[i] = tanhf(sp) * PI_F;
        rec[i] = dtv[i];
        float th = ang[i] * dtv[i];        // full angle; RY folded into meas rotation
        rec[6 + i]  = cosf(th);
        rec[12 + i] = sinf(th);
    }
    float C[6];
#pragma unroll
    for (int i = 0; i < 6; i++) {
        float s = 0.f;
#pragma unroll
        for (int k = 0; k < 6; k++) s += ang[k] * Wx[(9 + i) * 6 + k];
        C[i] = s;
    }
#pragma unroll
    for (int j = 0; j < 18; j++) {
        float s = 0.f;
#pragma unroll
        for (int i = 0; i < 6; i++) s += C[i] * Wc[j * 6 + i];
        rec[18 + j] = s;
        rec[36 + j] = D[j] * ang[j % 6];
    }
}

// ---------------------------------------------------------------------------
// Packed layout: lanes 0-31 hold the 64-amp state, 2 amps/lane (reg r = q2 bit).
// amp bits (a5..a0) = (q0..q5);  amp = (bit2(l)<<5)|(bit3(l)<<4)|(r<<3)|(bit0(l)<<2)|(bit1(l)<<1)|bit4(l)
// lane masks: q0=4, q1=8, q2=reg, q3=1, q4=2, q5=16.  Upper 32 lanes duplicate.
// ---------------------------------------------------------------------------
__global__ __launch_bounds__(64, 1) void step_kernel(
    const float* __restrict__ sd, const float* __restrict__ pc,
    const float* __restrict__ qp, const float* __restrict__ cp,
    float* __restrict__ out)
{
    const int lane = threadIdx.x;
    const int b = blockIdx.x;
    const int l5 = lane & 31;
    const float inv64 = 0.015625f;

    const int bq0 = (l5 >> 2) & 1, bq1 = (l5 >> 3) & 1;
    const int bq3 = l5 & 1,        bq4 = (l5 >> 1) & 1, bq5 = (l5 >> 4) & 1;

    // Walsh signs
    const float s3 = 1.f - 2.f * bq3, s4 = 1.f - 2.f * bq4, s34 = s3 * s4;
    const float sA = 1.f - 2.f * bq0, sB = 1.f - 2.f * bq1, sC = 1.f - 2.f * bq5;
    const float sAB = sA * sB, sAC = sA * sC, sBC = sB * sC, sABC = sAB * sC;

    // radix-8 butterflies: low dims {reg,1,2} handled by caller+this; high {4,8,16}
    auto bL = [&](float v) {
        float a = shxm<1>(v), bb = shxm<2>(v), c = shxm<3>(v);
        return fmaf(s34, v, fmaf(s4, a, fmaf(s3, bb, c)));
    };
    auto bH = [&](float v) {
        float v4 = shxm<4>(v), v8 = shxm<8>(v), v12 = shxm<12>(v);
        float v16 = shxm<16>(v), v20 = shxm<20>(v), v24 = shxm<24>(v), v28 = shxm<28>(v);
        return fmaf(sABC, v, fmaf(sBC, v4, fmaf(sAC, v8, fmaf(sC, v12,
               fmaf(sAB, v16, fmaf(sB, v20, fmaf(sA, v24, v28)))))));
    };
    auto walsh2 = [&](float& p0, float& p1) {
        float e0 = p0 + p1, e1 = p0 - p1;
        p0 = bH(bL(e0)); p1 = bH(bL(e1));
    };

    // writer lanes hold coefficient positions: amp mask of qubit -> (lane,reg)
    // q0->(4,0) q1->(8,0) q2->(0,1) q3->(1,0) q4->(2,0) q5->(16,0)
    const bool isw = (lane == 4 || lane == 8 || lane == 0 || lane == 1 || lane == 2 || lane == 16);
    const int qi = (lane == 4) ? 0 : (lane == 8) ? 1 : (lane == 0) ? 2 :
                   (lane == 1) ? 3 : (lane == 2) ? 4 : (lane == 16) ? 5 : 0;
    const bool lane0sel = (lane == 0);

    // amp indices + QSVT collapse (A coefs, permuted-bit selects) per reg
    int ampv[2];
    float A[2][6], sel[2][6];
    float frS[2], fiS[2];
#pragma unroll
    for (int r = 0; r < 2; r++) {
        int a = (bq0 << 5) | (bq1 << 4) | (r << 3) | (bq3 << 2) | (bq4 << 1) | bq5;
        ampv[r] = a;
        int x1 = permf(a), x2 = permf(x1), x3 = permf(x2), x4 = permf(x3);
#pragma unroll
        for (int i = 0; i < 6; i++) {
            float u0 = pc[0] * PI_F * qp[0 * 6 + i];
            float u1 = pc[1] * PI_F * qp[1 * 6 + i];
            float u2 = pc[2] * PI_F * qp[2 * 6 + i];
            float u3 = pc[3] * PI_F;
            float g1 = ((x1 >> (5 - i)) & 1) ? 0.5f : -0.5f;
            float g2 = ((x2 >> (5 - i)) & 1) ? 0.5f : -0.5f;
            float g3 = ((x3 >> (5 - i)) & 1) ? 0.5f : -0.5f;
            float g4 = ((x4 >> (5 - i)) & 1) ? 0.5f : -0.5f;
            A[r][i] = u3 * g1 + u2 * g2 + u1 * g3 + u0 * g4;
            sel[r][i] = (float)((x4 >> (5 - i)) & 1);   // permuted product-state bit select
        }
        int kk = __popc(a) & 3;   // S-dagger factor (-i)^popc
        frS[r] = (kk == 0) ? 1.f : ((kk == 2) ? -1.f : 0.f);
        fiS[r] = (kk == 1) ? -1.f : ((kk == 3) ? 1.f : 0.f);
    }

    // ---- fused ansatz coefficients (t-independent) ----
    float qc01[2][8], qc23[2][2][8], qc45[2][8];
    float rc1[2][4], rc2[2][2][4], rc3[2][4], rc4[2][4], rc5[2][2][4], rc6[2][4];
#pragma unroll
    for (int l = 0; l < 2; l++) {
        float g00r[6], g00i[6], g01r[6], g01i[6], g10r[6], g10i[6], g11r[6], g11i[6];
#pragma unroll
        for (int i = 0; i < 6; i++) {
            float ax = cp[l * 30 + i * 3 + 0];
            float ay = cp[l * 30 + i * 3 + 1];
            float az = cp[l * 30 + i * 3 + 2];
            float ca = cosf(0.5f * ax), sa = sinf(0.5f * ax);
            float cb = cosf(0.5f * ay), sb = sinf(0.5f * ay);
            float cg = cosf(0.5f * az), sg = sinf(0.5f * az);
            float m00r = cb * ca, m00i =  sb * sa;
            float m01r = -sb * ca, m01i = -cb * sa;
            float m10r =  sb * ca, m10i = -cb * sa;
            float m11r =  cb * ca, m11i = -sb * sa;
            g00r[i] = cg * m00r + sg * m00i; g00i[i] = cg * m00i - sg * m00r;
            g01r[i] = cg * m01r + sg * m01i; g01i[i] = cg * m01i - sg * m01r;
            g10r[i] = cg * m10r - sg * m10i; g10i[i] = cg * m10i + sg * m10r;
            g11r[i] = cg * m11r - sg * m11i; g11i[i] = cg * m11i + sg * m11r;
        }
        auto mkqc = [&](float* c, int aq, int ba, int bq, int bb) {
            float dar = ba ? g11r[aq] : g00r[aq], dai = ba ? g11i[aq] : g00i[aq];
            float oar = ba ? g10r[aq] : g01r[aq], oai = ba ? g10i[aq] : g01i[aq];
            float dbr = bb ? g11r[bq] : g00r[bq], dbi = bb ? g11i[bq] : g00i[bq];
            float obr = bb ? g10r[bq] : g01r[bq], obi = bb ? g10i[bq] : g01i[bq];
            c[0] = dar * dbr - dai * dbi;  c[1] = dar * dbi + dai * dbr;
            c[2] = oar * dbr - oai * dbi;  c[3] = oar * dbi + oai * dbr;
            c[4] = dar * obr - dai * obi;  c[5] = dar * obi + dai * obr;
            c[6] = oar * obr - oai * obi;  c[7] = oar * obi + oai * obr;
        };
        mkqc(qc01[l], 0, bq0, 1, bq1);
        mkqc(qc23[l][0], 2, 0, 3, bq3);
        mkqc(qc23[l][1], 2, 1, 3, bq3);
        mkqc(qc45[l], 4, bq4, 5, bq5);
        auto mkrc = [&](float* rc, float tha, float thb, int ba, int bb) {
            float ca = cosf(0.5f * tha), sa = sinf(0.5f * tha);
            float cb = cosf(0.5f * thb), sb = sinf(0.5f * thb);
            float mx0 = ba ? ca : 1.f, sae = ba ? sa : 0.f;
            float ny0 = bb ? cb : 1.f, sbe = bb ? sb : 0.f;
            rc[0] = ny0 * mx0; rc[1] = -ny0 * sae; rc[2] = -mx0 * sbe; rc[3] = -sae * sbe;
        };
        const float* cpl = cp + l * 30;
        mkrc(rc1[l],    cpl[18], cpl[19], bq0, bq1);  // (0->1)(1->2)
        mkrc(rc2[l][0], cpl[20], cpl[21], 0,   bq3);  // (2->3)(3->4), q2=0
        mkrc(rc2[l][1], cpl[20], cpl[21], 1,   bq3);
        mkrc(rc3[l],    cpl[22], cpl[23], bq4, bq5);  // (4->5)(5->0)
        mkrc(rc4[l],    cpl[24], cpl[25], bq5, bq4);  // (5->4)(4->3)
        mkrc(rc5[l][0], cpl[26], cpl[27], bq3, 0);    // (3->2)(2->1), q2=0
        mkrc(rc5[l][1], cpl[26], cpl[27], bq3, 1);
        mkrc(rc6[l],    cpl[28], cpl[29], bq1, bq0);  // (1->0)(0->5)
    }

    const float* sdb = sd + (size_t)b * SEQ * SD_STRIDE;
    float* outb = out + (size_t)b * SEQ * 18;

    float h0 = 0.f, h1 = 0.f, h2 = 0.f, h3 = 0.f, h4 = 0.f, h5 = 0.f;
    // deferred-Y / store pipeline state
    float ysr0 = 0.f, ysi0 = 0.f, ysr1 = 0.f, ysi1 = 0.f;
    float pxm = 0.f, pzm = 0.f;
    float pcx = 0.f, pcy = 0.f, pcz = 0.f, ptx = 0.f, pty = 0.f, ptz = 0.f;

    // Y of saved state: S^dag twist, complex Walsh, square, Walsh (x 1/64 at use)
    auto ymeas = [&](float ar0, float ai0, float ar1, float ai1, float& y0, float& y1) {
        float cr0 = frS[0] * ar0 - fiS[0] * ai0, ci0 = frS[0] * ai0 + fiS[0] * ar0;
        float cr1 = frS[1] * ar1 - fiS[1] * ai1, ci1 = frS[1] * ai1 + fiS[1] * ar1;
        float er0 = cr0 + cr1, er1 = cr0 - cr1, ei0 = ci0 + ci1, ei1 = ci0 - ci1;
        er0 = bH(bL(er0)); er1 = bH(bL(er1)); ei0 = bH(bL(ei0)); ei1 = bH(bL(ei1));
        y0 = er0 * er0 + ei0 * ei0; y1 = er1 * er1 + ei1 * ei1;
        walsh2(y0, y1);
    };

    for (int t = 0; t < SEQ; t++) {
        const float* r = sdb + t * SD_STRIDE;
        float d0 = r[0], d1 = r[1], d2 = r[2], d3 = r[3], d4 = r[4], d5 = r[5];

        // deferred Y(t-1) + store(t-1): independent of the h critical chain
        float yw0, yw1;
        ymeas(ysr0, ysi0, ysr1, ysi1, yw0, yw1);
        if (isw && t > 0) {
            float ymv = (lane0sel ? yw1 : yw0) * inv64;
            float* o = outb + (size_t)(t - 1) * 18;
            o[qi]      = fmaf(pcx, pxm, ptx);
            o[6 + qi]  = fmaf(pcy, ymv, pty);
            o[12 + qi] = fmaf(pcz, pzm, ptz);
        }

        // ---- product state RY(h)|0..0>, already sigma^4-permuted (bit selects) ----
        float cc0, ss0, cc1, ss1, cc2, ss2, cc3, ss3, cc4, ss4, cc5, ss5;
        __sincosf(0.5f * h0, &ss0, &cc0);
        __sincosf(0.5f * h1, &ss1, &cc1);
        __sincosf(0.5f * h2, &ss2, &cc2);
        __sincosf(0.5f * h3, &ss3, &cc3);
        __sincosf(0.5f * h4, &ss4, &cc4);
        __sincosf(0.5f * h5, &ss5, &cc5);
        float dd0 = ss0 - cc0, dd1 = ss1 - cc1, dd2 = ss2 - cc2;
        float dd3 = ss3 - cc3, dd4 = ss4 - cc4, dd5 = ss5 - cc5;
        float prod0, prod1;
        {
            float f0 = fmaf(sel[0][0], dd0, cc0), f1 = fmaf(sel[0][1], dd1, cc1);
            float f2 = fmaf(sel[0][2], dd2, cc2), f3 = fmaf(sel[0][3], dd3, cc3);
            float f4 = fmaf(sel[0][4], dd4, cc4), f5 = fmaf(sel[0][5], dd5, cc5);
            prod0 = ((f0 * f1) * (f2 * f3)) * (f4 * f5);
            f0 = fmaf(sel[1][0], dd0, cc0); f1 = fmaf(sel[1][1], dd1, cc1);
            f2 = fmaf(sel[1][2], dd2, cc2); f3 = fmaf(sel[1][3], dd3, cc3);
            f4 = fmaf(sel[1][4], dd4, cc4); f5 = fmaf(sel[1][5], dd5, cc5);
            prod1 = ((f0 * f1) * (f2 * f3)) * (f4 * f5);
        }
        // ---- QSVT diagonal phase ----
        float phi0 = A[0][0]*d0 + A[0][1]*d1 + A[0][2]*d2 + A[0][3]*d3 + A[0][4]*d4 + A[0][5]*d5;
        float phi1 = A[1][0]*d0 + A[1][1]*d1 + A[1][2]*d2 + A[1][3]*d3 + A[1][4]*d4 + A[1][5]*d5;
        float sp0, cp0, sp1, cp1;
        __sincosf(phi0, &sp0, &cp0);
        __sincosf(phi1, &sp1, &cp1);
        float re0 = prod0 * cp0, im0 = prod0 * sp0;
        float re1 = prod1 * cp1, im1 = prod1 * sp1;

        // ---- ansatz: 2 layers ----
#pragma unroll
        for (int l = 0; l < 2; l++) {
            float n0r, n0i, n1r, n1i;
            {   // pair1q(q0,q1): masks 4,8,12
                float a0r = shxm<4>(re0), a0i = shxm<4>(im0), a1r = shxm<4>(re1), a1i = shxm<4>(im1);
                float b0r = shxm<8>(re0), b0i = shxm<8>(im0), b1r = shxm<8>(re1), b1i = shxm<8>(im1);
                float c0r = shxm<12>(re0), c0i = shxm<12>(im0), c1r = shxm<12>(re1), c1i = shxm<12>(im1);
                cmul4(qc01[l], re0, im0, a0r, a0i, b0r, b0i, c0r, c0i, n0r, n0i);
                cmul4(qc01[l], re1, im1, a1r, a1i, b1r, b1i, c1r, c1i, n1r, n1i);
                re0 = n0r; im0 = n0i; re1 = n1r; im1 = n1i;
            }
            {   // pair1q(q2,q3): reg + mask1 (DPP only)
                float d0r = shxm<1>(re0), d0i = shxm<1>(im0), d1r = shxm<1>(re1), d1i = shxm<1>(im1);
                cmul4(qc23[l][0], re0, im0, re1, im1, d0r, d0i, d1r, d1i, n0r, n0i);
                cmul4(qc23[l][1], re1, im1, re0, im0, d1r, d1i, d0r, d0i, n1r, n1i);
                re0 = n0r; im0 = n0i; re1 = n1r; im1 = n1i;
            }
            {   // pair1q(q4,q5): masks 2,16,18
                float a0r = shxm<2>(re0), a0i = shxm<2>(im0), a1r = shxm<2>(re1), a1i = shxm<2>(im1);
                float b0r = shxm<16>(re0), b0i = shxm<16>(im0), b1r = shxm<16>(re1), b1i = shxm<16>(im1);
                float c0r = shxm<18>(re0), c0i = shxm<18>(im0), c1r = shxm<18>(re1), c1i = shxm<18>(im1);
                cmul4(qc45[l], re0, im0, a0r, a0i, b0r, b0i, c0r, c0i, n0r, n0i);
                cmul4(qc45[l], re1, im1, a1r, a1i, b1r, b1i, c1r, c1i, n1r, n1i);
                re0 = n0r; im0 = n0i; re1 = n1r; im1 = n1i;
            }
            {   // ring (0->1)(1->2): b=q1(dpp8), c=q2(reg) — DPP only
                float b0r = shxm<8>(re0), b0i = shxm<8>(im0), b1r = shxm<8>(re1), b1i = shxm<8>(im1);
                ringapply(rc1[l], re0, im0, b0r, b0i, re1, im1, b1r, b1i, n0r, n0i);
                ringapply(rc1[l], re1, im1, b1r, b1i, re0, im0, b0r, b0i, n1r, n1i);
                re0 = n0r; im0 = n0i; re1 = n1r; im1 = n1i;
            }
            {   // ring (2->3)(3->4): b=q3(1), c=q4(2), d=3 — DPP only
                float b0r = shxm<1>(re0), b0i = shxm<1>(im0), b1r = shxm<1>(re1), b1i = shxm<1>(im1);
                float c0r = shxm<2>(re0), c0i = shxm<2>(im0), c1r = shxm<2>(re1), c1i = shxm<2>(im1);
                float e0r = shxm<3>(re0), e0i = shxm<3>(im0), e1r = shxm<3>(re1), e1i = shxm<3>(im1);
                ringapply(rc2[l][0], re0, im0, b0r, b0i, c0r, c0i, e0r, e0i, n0r, n0i);
                ringapply(rc2[l][1], re1, im1, b1r, b1i, c1r, c1i, e1r, e1i, n1r, n1i);
                re0 = n0r; im0 = n0i; re1 = n1r; im1 = n1i;
            }
            {   // ring (4->5)(5->0): b=q5(16), c=q0(4), d=20
                float b0r = shxm<16>(re0), b0i = shxm<16>(im0), b1r = shxm<16>(re1), b1i = shxm<16>(im1);
                float c0r = shxm<4>(re0), c0i = shxm<4>(im0), c1r = shxm<4>(re1), c1i = shxm<4>(im1);
                float e0r = shxm<20>(re0), e0i = shxm<20>(im0), e1r = shxm<20>(re1), e1i = shxm<20>(im1);
                ringapply(rc3[l], re0, im0, b0r, b0i, c0r, c0i, e0r, e0i, n0r, n0i);
                ringapply(rc3[l], re1, im1, b1r, b1i, c1r, c1i, e1r, e1i, n1r, n1i);
                re0 = n0r; im0 = n0i; re1 = n1r; im1 = n1i;
            }
            {   // ring (5->4)(4->3): b=q4(2), c=q3(1), d=3 — DPP only
                float b0r = shxm<2>(re0), b0i = shxm<2>(im0), b1r = shxm<2>(re1), b1i = shxm<2>(im1);
                float c0r = shxm<1>(re0), c0i = shxm<1>(im0), c1r = shxm<1>(re1), c1i = shxm<1>(im1);
                float e0r = shxm<3>(re0), e0i = shxm<3>(im0), e1r = shxm<3>(re1), e1i = shxm<3>(im1);
                ringapply(rc4[l], re0, im0, b0r, b0i, c0r, c0i, e0r, e0i, n0r, n0i);
                ringapply(rc4[l], re1, im1, b1r, b1i, c1r, c1i, e1r, e1i, n1r, n1i);
                re0 = n0r; im0 = n0i; re1 = n1r; im1 = n1i;
            }
            {   // ring (3->2)(2->1): b=q2(reg), c=q1(dpp8) — DPP only
                float e0r = shxm<8>(re0), e0i = shxm<8>(im0), e1r = shxm<8>(re1), e1i = shxm<8>(im1);
                ringapply(rc5[l][0], re0, im0, re1, im1, e0r, e0i, e1r, e1i, n0r, n0i);
                ringapply(rc5[l][1], re1, im1, re0, im0, e1r, e1i, e0r, e0i, n1r, n1i);
                re0 = n0r; im0 = n0i; re1 = n1r; im1 = n1i;
            }
            {   // ring (1->0)(0->5): b=q0(4), c=q5(16), d=20
                float b0r = shxm<4>(re0), b0i = shxm<4>(im0), b1r = shxm<4>(re1), b1i = shxm<4>(im1);
                float c0r = shxm<16>(re0), c0i = shxm<16>(im0), c1r = shxm<16>(re1), c1i = shxm<16>(im1);
                float e0r = shxm<20>(re0), e0i = shxm<20>(im0), e1r = shxm<20>(re1), e1i = shxm<20>(im1);
                ringapply(rc6[l], re0, im0, b0r, b0i, c0r, c0i, e0r, e0i, n0r, n0i);
                ringapply(rc6[l], re1, im1, b1r, b1i, c1r, c1i, e1r, e1i, n1r, n1i);
                re0 = n0r; im0 = n0i; re1 = n1r; im1 = n1i;
            }
        }

        // ---- Z: Walsh(|psi|^2) ----
        float wz0 = re0 * re0 + im0 * im0;
        float wz1 = re1 * re1 + im1 * im1;
        walsh2(wz0, wz1);
        // ---- X: |WalshC(psi)|^2 then Walsh, x1/64 ----
        float er0 = re0 + re1, er1 = re0 - re1, ei0 = im0 + im1, ei1 = im0 - im1;
        er0 = bH(bL(er0)); er1 = bH(bL(er1)); ei0 = bH(bL(ei0)); ei1 = bH(bL(ei1));
        float wx0 = er0 * er0 + ei0 * ei0;
        float wx1 = er1 * er1 + ei1 * ei1;
        walsh2(wx0, wx1);

        // ---- h feedback: readlane -> wave-uniform (lower half authoritative) ----
        float Z0 = rdl<4>(wz0), Z1 = rdl<8>(wz0), Z2 = rdl<0>(wz1);
        float Z3 = rdl<1>(wz0), Z4 = rdl<2>(wz0), Z5 = rdl<16>(wz0);
        float X0 = rdl<4>(wx0) * inv64, X1 = rdl<8>(wx0) * inv64, X2 = rdl<0>(wx1) * inv64;
        float X3 = rdl<1>(wx0) * inv64, X4 = rdl<2>(wx0) * inv64, X5 = rdl<16>(wx0) * inv64;
        h0 = r[6]  * Z0 - r[12] * X0;
        h1 = r[7]  * Z1 - r[13] * X1;
        h2 = r[8]  * Z2 - r[14] * X2;
        h3 = r[9]  * Z3 - r[15] * X3;
        h4 = r[10] * Z4 - r[16] * X4;
        h5 = r[11] * Z5 - r[17] * X5;

        // ---- save pipeline state for the deferred store of step t ----
        float Mz = lane0sel ? wz1 : wz0;
        float Mx = (lane0sel ? wx1 : wx0) * inv64;
        float ctl = r[6 + qi], stl = r[12 + qi];
        pzm = ctl * Mz - stl * Mx;
        pxm = ctl * Mx + stl * Mz;
        pcx = r[18 + qi]; pcy = r[24 + qi]; pcz = r[30 + qi];
        ptx = r[36 + qi]; pty = r[42 + qi]; ptz = r[48 + qi];
        ysr0 = re0; ysi0 = im0; ysr1 = re1; ysi1 = im1;
    }
    // epilogue: Y + store for t = SEQ-1
    float yw0, yw1;
    ymeas(ysr0, ysi0, ysr1, ysi1, yw0, yw1);
    if (isw) {
        float ymv = (lane0sel ? yw1 : yw0) * inv64;
        float* o = outb + (size_t)(SEQ - 1) * 18;
        o[qi]      = fmaf(pcx, pxm, ptx);
        o[6 + qi]  = fmaf(pcy, ymv, pty);
        o[12 + qi] = fmaf(pcz, pzm, ptz);
    }
}

// ---------------------------------------------------------------------------
extern "C" void kernel_launch(void* const* d_in, const int* in_sizes, int n_in,
                              void* d_out, int out_size, void* d_ws, size_t ws_size,
                              hipStream_t stream) {
    const float* angles = (const float*)d_in[0];
    const float* Wx     = (const float*)d_in[1];
    const float* Wdt    = (const float*)d_in[2];
    const float* bdt    = (const float*)d_in[3];
    const float* pc     = (const float*)d_in[4];
    const float* qp     = (const float*)d_in[5];
    const float* cp     = (const float*)d_in[6];
    const float* D      = (const float*)d_in[7];
    const float* Wc     = (const float*)d_in[8];
    float* sd  = (float*)d_ws;
    float* out = (float*)d_out;

    prep_kernel<<<(BATCH * SEQ) / 256, 256, 0, stream>>>(angles, Wx, Wdt, bdt, D, Wc, sd);
    step_kernel<<<BATCH, 64, 0, stream>>>(sd, pc, qp, cp, out);
}